// Round 7
// baseline (338.394 us; speedup 1.0000x reference)
//
#include <hip/hip_runtime.h>

#define N_NODES 100000
#define N_EDGES 1600000
#define NEG_SLOPE 0.2f

#define NBKT 512          // buckets (510 used + tail)
#define BDIV 196          // nodes per bucket: ceil-ish, 510*196=99960, last bucket 40 nodes
#define NUSED 511         // buckets actually populated
#define PB 250            // partition blocks
#define QPB 1600          // quads per partition block (6400 edges)
#define PBS 256           // histT stride (padded 250->256)
#define NP2 400           // nodes per k_part block (250*400 = 100000)

typedef int   vint4   __attribute__((ext_vector_type(4)));
typedef int   vint2   __attribute__((ext_vector_type(2)));
typedef float vfloat4 __attribute__((ext_vector_type(4)));

__device__ __forceinline__ float leaky(float v) { return v >= 0.f ? v : NEG_SLOPE * v; }

// ---------- P0: per-block bucket histogram ----------
__global__ void __launch_bounds__(256) k_hist(const int* __restrict__ ei,
                                              int* __restrict__ histT) {
    __shared__ int hist[NBKT];
    int tid = threadIdx.x;
    hist[tid] = 0;
    hist[tid + 256] = 0;
    __syncthreads();
    const vint4* dst4 = (const vint4*)(ei + N_EDGES);
    int q0 = blockIdx.x * QPB;
    for (int q = tid; q < QPB; q += 256) {
        vint4 d = __builtin_nontemporal_load(&dst4[q0 + q]);
        atomicAdd(&hist[d.x / BDIV], 1);
        atomicAdd(&hist[d.y / BDIV], 1);
        atomicAdd(&hist[d.z / BDIV], 1);
        atomicAdd(&hist[d.w / BDIV], 1);
    }
    __syncthreads();
    histT[tid * PBS + blockIdx.x] = hist[tid];             // bucket-major
    histT[(tid + 256) * PBS + blockIdx.x] = hist[tid + 256];
}

// ---------- P1: scan 512x250 table -> exact offsets; fused attention consts ----------
// consts[0..7] cS1[r][h]; [8..15] cD1[r][h]; [16..19] cE1[h]
__global__ void __launch_bounds__(1024) k_scan(const int* __restrict__ histT,
                                               int* __restrict__ offT,
                                               int* __restrict__ bbase,
                                               int* __restrict__ bcnt,
                                               const float* __restrict__ W1,
                                               const float* __restrict__ attS1,
                                               const float* __restrict__ attD1,
                                               const float* __restrict__ We1,
                                               const float* __restrict__ attE1,
                                               float* __restrict__ consts) {
    __shared__ int psum[1024];
    __shared__ int btot[NBKT];
    int tid = threadIdx.x;
    if (tid < 8) {
        int r = tid >> 2, h = tid & 3;
        float s = 0.f;
        for (int c = 0; c < 32; ++c) s += W1[r * 128 + h * 32 + c] * attS1[h * 32 + c];
        consts[tid] = s;
    } else if (tid < 16) {
        int u = tid - 8, r = u >> 2, h = u & 3;
        float s = 0.f;
        for (int c = 0; c < 32; ++c) s += W1[r * 128 + h * 32 + c] * attD1[h * 32 + c];
        consts[tid] = s;
    } else if (tid < 20) {
        int h = tid - 16;
        float s = 0.f;
        for (int c = 0; c < 32; ++c) s += We1[h * 32 + c] * attE1[h * 32 + c];
        consts[tid] = s;
    }
    int b = tid >> 1, q = tid & 1;
    int s = 0;
    for (int k = 0; k < 125; ++k) s += histT[b * PBS + q * 125 + k];
    psum[tid] = s;
    __syncthreads();
    int mytot = 0;
    if (tid < NBKT) {
        mytot = psum[2 * tid] + psum[2 * tid + 1];
        btot[tid] = mytot;
    }
    __syncthreads();
    for (int off = 1; off < NBKT; off <<= 1) {
        int t = (tid < NBKT && tid >= off) ? btot[tid - off] : 0;
        __syncthreads();
        if (tid < NBKT) btot[tid] += t;
        __syncthreads();
    }
    if (tid < NBKT) {
        int excl = btot[tid] - mytot;
        bbase[tid] = excl;
        bcnt[tid] = mytot;
        btot[tid] = excl;
    }
    __syncthreads();
    int run = btot[b] + (q ? psum[2 * b] : 0);
    for (int k = 0; k < 125; ++k) {
        int pb = q * 125 + k;
        int c = histT[b * PBS + pb];
        offT[pb * NBKT + b] = run;
        run += c;
    }
}

// ---------- P2: partition edges to bucket-grouped staging + fused node records ----------
// Each (block,bucket) staging segment is single-writer & contiguous -> writes
// combine in this CU's L2 regardless of XCD placement.
__global__ void __launch_bounds__(256) k_part(const int* __restrict__ ei,
                                              const float* __restrict__ w,
                                              const int* __restrict__ offT,
                                              const float* __restrict__ x,
                                              const float* __restrict__ consts,
                                              int2* __restrict__ staging,
                                              float* __restrict__ nodeRec,
                                              float* __restrict__ aD1) {
    __shared__ int lcur[NBKT];
    int tid = threadIdx.x;
    lcur[tid] = offT[blockIdx.x * NBKT + tid];
    lcur[tid + 256] = offT[blockIdx.x * NBKT + tid + 256];
    __syncthreads();
    const vint4* src4 = (const vint4*)ei;
    const vint4* dst4 = (const vint4*)(ei + N_EDGES);
    const vfloat4* w4 = (const vfloat4*)w;
    int q0 = blockIdx.x * QPB;
    for (int q = tid; q < QPB; q += 256) {
        vint4 s = __builtin_nontemporal_load(&src4[q0 + q]);
        vint4 d = __builtin_nontemporal_load(&dst4[q0 + q]);
        vfloat4 ww = __builtin_nontemporal_load(&w4[q0 + q]);
#pragma unroll
        for (int j = 0; j < 4; ++j) {
            int dd = (j == 0) ? d.x : (j == 1) ? d.y : (j == 2) ? d.z : d.w;
            int ss = (j == 0) ? s.x : (j == 1) ? s.y : (j == 2) ? s.z : s.w;
            float wv = (j == 0) ? ww.x : (j == 1) ? ww.y : (j == 2) ? ww.z : ww.w;
            int b = dd / BDIV;
            int pos = atomicAdd(&lcur[b], 1);
            staging[pos] = make_int2(ss | ((dd - b * BDIV) << 17), __float_as_int(wv));
        }
    }
    // fused per-node records for nodes [blockIdx*400, +400)
    for (int j = tid; j < NP2; j += 256) {
        int n = blockIdx.x * NP2 + j;
        float x0 = x[2 * n], x1 = x[2 * n + 1];
#pragma unroll
        for (int h = 0; h < 4; ++h) {
            nodeRec[n * 8 + h] = x0 * consts[h] + x1 * consts[4 + h];
            aD1[n * 4 + h]     = x0 * consts[8 + h] + x1 * consts[12 + h];
        }
        nodeRec[n * 8 + 4] = x0;
        nodeRec[n * 8 + 5] = x1;
        nodeRec[n * 8 + 6] = 0.f;
        nodeRec[n * 8 + 7] = 0.f;
    }
}

// ---------- P3: layer-1 per bucket: LDS-atomic softmax accumulate + MLP -> h2 ----------
__global__ void __launch_bounds__(256) k_layer1(const int* __restrict__ bbase,
                                                const int* __restrict__ bcnt,
                                                const int2* __restrict__ staging,
                                                const float* __restrict__ nodeRec,
                                                const float* __restrict__ aD1,
                                                const float* __restrict__ consts,
                                                const float* __restrict__ W1,
                                                const float* __restrict__ b1,
                                                const float* __restrict__ W2,
                                                float* __restrict__ h2) {
    __shared__ float sA[BDIV * 4], X0A[BDIV * 4], X1A[BDIV * 4], adL[BDIV * 4];
    __shared__ float wsumA[BDIV], cntA[BDIV];
    __shared__ float w10[132], w11[132], b1s[132], w2s[132];
    int b = blockIdx.x, tid = threadIdx.x;
    int n0 = b * BDIV;
    int nnode = min(BDIV, N_NODES - n0);
    for (int j = tid; j < BDIV * 4; j += 256) {
        sA[j] = 0.f; X0A[j] = 0.f; X1A[j] = 0.f;
        adL[j] = (j < nnode * 4) ? aD1[n0 * 4 + j] : 0.f;
    }
    for (int j = tid; j < BDIV; j += 256) { wsumA[j] = 0.f; cntA[j] = 0.f; }
    for (int j = tid; j < 128; j += 256) {
        int jj = (j >> 5) * 33 + (j & 31);
        w10[jj] = W1[j]; w11[jj] = W1[128 + j]; b1s[jj] = b1[j]; w2s[jj] = W2[j];
    }
    float cE0 = consts[16], cE1 = consts[17], cE2 = consts[18], cE3 = consts[19];
    __syncthreads();
    int base = bbase[b], cnt = bcnt[b];
    const vint2* st2 = (const vint2*)staging;
    for (int i = tid; i < cnt; i += 256) {
        vint2 e = __builtin_nontemporal_load(&st2[base + i]);
        int src = e.x & 0x1FFFF;
        int dl = e.x >> 17;
        float wt = __int_as_float(e.y);
        vfloat4 as = *(const vfloat4*)(nodeRec + src * 8);
        vfloat4 xs = *(const vfloat4*)(nodeRec + src * 8 + 4);
        float p0 = __expf(leaky(as.x + adL[dl * 4 + 0] + wt * cE0));
        float p1 = __expf(leaky(as.y + adL[dl * 4 + 1] + wt * cE1));
        float p2 = __expf(leaky(as.z + adL[dl * 4 + 2] + wt * cE2));
        float p3 = __expf(leaky(as.w + adL[dl * 4 + 3] + wt * cE3));
        atomicAdd(&sA[dl * 4 + 0], p0);  atomicAdd(&sA[dl * 4 + 1], p1);
        atomicAdd(&sA[dl * 4 + 2], p2);  atomicAdd(&sA[dl * 4 + 3], p3);
        atomicAdd(&X0A[dl * 4 + 0], p0 * xs.x);  atomicAdd(&X0A[dl * 4 + 1], p1 * xs.x);
        atomicAdd(&X0A[dl * 4 + 2], p2 * xs.x);  atomicAdd(&X0A[dl * 4 + 3], p3 * xs.x);
        atomicAdd(&X1A[dl * 4 + 0], p0 * xs.y);  atomicAdd(&X1A[dl * 4 + 1], p1 * xs.y);
        atomicAdd(&X1A[dl * 4 + 2], p2 * xs.y);  atomicAdd(&X1A[dl * 4 + 3], p3 * xs.y);
        atomicAdd(&wsumA[dl], wt);
        atomicAdd(&cntA[dl], 1.f);
    }
    __syncthreads();
    for (int j = tid; j < nnode; j += 256) {
        int n = n0 + j;
        float d = cntA[j];
        float la = wsumA[j] / fmaxf(d, 1.f);
        vfloat4 aso = *(const vfloat4*)(nodeRec + n * 8);
        vfloat4 xo = *(const vfloat4*)(nodeRec + n * 8 + 4);
        float asov[4] = {aso.x, aso.y, aso.z, aso.w};
        float cE[4] = {cE0, cE1, cE2, cE3};
        float acc = 0.f;
#pragma unroll
        for (int h = 0; h < 4; ++h) {
            float p = __expf(leaky(asov[h] + adL[j * 4 + h] + la * cE[h]));
            float sh = sA[j * 4 + h] + p;
            float inv = 1.f / (sh + 1e-16f);
            float X0h = (X0A[j * 4 + h] + p * xo.x) * inv;
            float X1h = (X1A[j * 4 + h] + p * xo.y) * inv;
            int bj = h * 33;
            for (int c = 0; c < 32; ++c) {
                float v = X0h * w10[bj + c] + X1h * w11[bj + c] + b1s[bj + c];
                float el = v > 0.f ? v : __expf(v) - 1.f;  // elu
                acc += el * w2s[bj + c];
            }
        }
        h2[n] = acc;
    }
}

// ---------- P4: layer-2 per bucket -> out ----------
__global__ void __launch_bounds__(256) k_layer2(const int* __restrict__ bbase,
                                                const int* __restrict__ bcnt,
                                                const int2* __restrict__ staging,
                                                const float* __restrict__ h2,
                                                const float* __restrict__ attS2,
                                                const float* __restrict__ attD2,
                                                const float* __restrict__ We2,
                                                const float* __restrict__ attE2,
                                                const float* __restrict__ b2,
                                                float* __restrict__ out) {
    __shared__ float h2L[BDIV], s2A[BDIV], a2A[BDIV], wsA[BDIV], cA[BDIV];
    int b = blockIdx.x, tid = threadIdx.x;
    int n0 = b * BDIV;
    int nnode = min(BDIV, N_NODES - n0);
    for (int j = tid; j < BDIV; j += 256) {
        h2L[j] = (j < nnode) ? h2[n0 + j] : 0.f;
        s2A[j] = 0.f; a2A[j] = 0.f; wsA[j] = 0.f; cA[j] = 0.f;
    }
    float aS = attS2[0], aD = attD2[0], cE = We2[0] * attE2[0], bb = b2[0];
    __syncthreads();
    int base = bbase[b], cnt = bcnt[b];
    const vint2* st2 = (const vint2*)staging;
    for (int i = tid; i < cnt; i += 256) {
        vint2 e = __builtin_nontemporal_load(&st2[base + i]);
        int src = e.x & 0x1FFFF;
        int dl = e.x >> 17;
        float wt = __int_as_float(e.y);
        float hs = h2[src];
        float p = __expf(leaky(hs * aS + h2L[dl] * aD + wt * cE));
        atomicAdd(&s2A[dl], p);
        atomicAdd(&a2A[dl], p * hs);
        atomicAdd(&wsA[dl], wt);
        atomicAdd(&cA[dl], 1.f);
    }
    __syncthreads();
    for (int j = tid; j < nnode; j += 256) {
        float la = wsA[j] / fmaxf(cA[j], 1.f);
        float hn = h2L[j];
        float p = __expf(leaky(hn * aS + hn * aD + la * cE));
        float s = s2A[j] + p;
        float acc = a2A[j] + p * hn;
        out[n0 + j] = acc / (s + 1e-16f) + bb;
    }
}

extern "C" void kernel_launch(void* const* d_in, const int* in_sizes, int n_in,
                              void* d_out, int out_size, void* d_ws, size_t ws_size,
                              hipStream_t stream) {
    const float* x     = (const float*)d_in[0];
    const int*   ei    = (const int*)d_in[1];
    const float* w     = (const float*)d_in[2];
    const float* W1    = (const float*)d_in[3];
    const float* attS1 = (const float*)d_in[4];
    const float* attD1 = (const float*)d_in[5];
    const float* We1   = (const float*)d_in[6];
    const float* attE1 = (const float*)d_in[7];
    const float* b1    = (const float*)d_in[8];
    const float* W2    = (const float*)d_in[9];
    const float* attS2 = (const float*)d_in[10];
    const float* attD2 = (const float*)d_in[11];
    const float* We2   = (const float*)d_in[12];
    const float* attE2 = (const float*)d_in[13];
    const float* b2    = (const float*)d_in[14];
    float* out = (float*)d_out;

    const size_t N = N_NODES;

    // workspace layout (no zero-init needed anywhere)
    int*   histT   = (int*)d_ws;                      // NBKT*PBS   = 131072
    int*   offT    = histT + NBKT * PBS;              // PB*NBKT    = 128000
    int*   bbase   = offT + PB * NBKT;                // 512
    int*   bcnt    = bbase + NBKT;                    // 512
    float* consts  = (float*)(bcnt + NBKT);           // 32
    int2*  staging = (int2*)(consts + 32);            // E (8B-aligned)
    float* nodeRec = (float*)(staging + N_EDGES);     // 8N (16B-aligned)
    float* aD1     = nodeRec + 8 * N;                 // 4N
    float* h2      = aD1 + 4 * N;                     // N

    k_hist<<<PB, 256, 0, stream>>>(ei, histT);
    k_scan<<<1, 1024, 0, stream>>>(histT, offT, bbase, bcnt, W1, attS1, attD1, We1,
                                   attE1, consts);
    k_part<<<PB, 256, 0, stream>>>(ei, w, offT, x, consts, staging, nodeRec, aD1);
    k_layer1<<<NUSED, 256, 0, stream>>>(bbase, bcnt, staging, nodeRec, aD1, consts,
                                        W1, b1, W2, h2);
    k_layer2<<<NUSED, 256, 0, stream>>>(bbase, bcnt, staging, h2, attS2, attD2, We2,
                                        attE2, b2, out);
}